// Round 18
// baseline (5195.621 us; speedup 1.0000x reference)
//
#include <hip/hip_runtime.h>
#include <cstdint>

// ---------------------------------------------------------------------------
// Threefry-2x32 (JAX partitionable-mode compatible), host + device.
// ---------------------------------------------------------------------------
__host__ __device__ inline uint32_t tf_rotl32(uint32_t x, uint32_t r) {
  return (x << r) | (x >> (32u - r));
}

__host__ __device__ inline void threefry2x32(uint32_t k0, uint32_t k1,
                                             uint32_t x0, uint32_t x1,
                                             uint32_t* o0, uint32_t* o1) {
  uint32_t ks0 = k0, ks1 = k1, ks2 = k0 ^ k1 ^ 0x1BD11BDAu;
  x0 += ks0; x1 += ks1;
#define TF_R(r) { x0 += x1; x1 = tf_rotl32(x1, r); x1 ^= x0; }
  TF_R(13) TF_R(15) TF_R(26) TF_R(6)
  x0 += ks1; x1 += ks2 + 1u;
  TF_R(17) TF_R(29) TF_R(16) TF_R(24)
  x0 += ks2; x1 += ks0 + 2u;
  TF_R(13) TF_R(15) TF_R(26) TF_R(6)
  x0 += ks0; x1 += ks1 + 3u;
  TF_R(17) TF_R(29) TF_R(16) TF_R(24)
  x0 += ks1; x1 += ks2 + 4u;
  TF_R(13) TF_R(15) TF_R(26) TF_R(6)
  x0 += ks2; x1 += ks0 + 5u;
#undef TF_R
  *o0 = x0; *o1 = x1;
}

// ---------------------------------------------------------------------------
// Problem dims
// ---------------------------------------------------------------------------
#define BSZ   8192
#define KIN   784
#define HID   800
#define NOUT  10
#define NSTEP 25

// R8: golden = Eigen gebp (AVX no-FMA jaxlib): k-panels [0,264) [264,528)
// [528,784), per k-step acc = rn(acc + rn(a*b)); C = 0.5*rn(rn(P0+P1)+P2).
// R9: a in {0,1,2} makes every product exact, so fmaf == mul+add bit-exactly.
// R24-R26 (proven): B-in-SGPR (wave-uniform -> s_load_dwordx16, 1/kk at
//   BN=16), A lane-private via direct global dwordx4 (no LDS, no barriers).
//   R17 = 135.6us, occ 55.6%, VALU ~80us. Residual: SMEM chain + dispatch
//   tail (4800 blocks / ~7 resident = 2.7 rounds) + 78.6MB partial traffic.
// R27 (this round): full-K blocks — panel split moves from GRID to
//   REGISTERS. One block runs all 3 chains (k 0..263/264..527/528..783),
//   commits in-register (tot=acc; tot=rn(tot+acc)), writes g =
//   0.5*rn(tot+acc) directly. Grid 32x50 = 1600 blocks / 6400 waves ->
//   ~1 dispatch round (6.25 blocks/CU vs cap ~7) -> tail shrinks; WRITE
//   76.8->25.6MB; update reads 26 not 78.6MB. 264 is 8-but-not-16-aligned:
//   phases = {16 tiles + 8-tail}, {8-head + 16 tiles}, {16 tiles}; uint4
//   loads stay 16B-aligned, heads/tails uint2. Bit-identical rn sequence.
//   Predict gemm 135.6 -> 100-125, WRITE 25600; falsifier >=135 -> revert.
// ---------------------------------------------------------------------------

// ---------------------------------------------------------------------------
// Kernel 1: Poisson encoding (JAX-faithful: truncated 2^-23 grid).
// enc = temp + 1 in {0,1,2}; sp = 0.5*enc (exact power-of-2 relation).
// ---------------------------------------------------------------------------
__global__ __launch_bounds__(256) void enc_kernel(const float* __restrict__ inp,
                                                  uint8_t* __restrict__ enc,
                                                  uint32_t k0, uint32_t k1) {
  int j = blockIdx.x * blockDim.x + threadIdx.x;
  if (j >= BSZ * KIN) return;
  uint32_t o0, o1;
  threefry2x32(k0, k1, 0u, (uint32_t)j, &o0, &o1);
  uint32_t bits = o0 ^ o1;
  float r = __uint_as_float((bits >> 9) | 0x3f800000u) - 1.0f;
  float x = inp[j];
  bool cond = (2.0f * r <= fabsf(x));
  int s = (x > 0.0f) ? 1 : ((x < 0.0f) ? -1 : 0);
  enc[j] = (uint8_t)(1 + (cond ? s : 0));
}

// ---------------------------------------------------------------------------
// Kernel 1b: one-time transpose w1 [HID][KIN] -> w1t [KIN][HID] (pure copy,
// bit-exact values; makes B rows contiguous for scalar loads).
// ---------------------------------------------------------------------------
__global__ __launch_bounds__(256) void transpose_kernel(const float* __restrict__ w1,
                                                        float* __restrict__ w1t) {
  int idx = blockIdx.x * blockDim.x + threadIdx.x;
  if (idx >= KIN * HID) return;
  int k = idx / HID, n = idx % HID;
  w1t[idx] = w1[(size_t)n * KIN + k];
}

// ---------------------------------------------------------------------------
// Kernel 2: g[b,j] = 0.5 * rn(rn(P0+P1)+P2), all three Eigen panel chains
// in one block (full K), commits in registers.
// BM=256 (4 waves x 64 rows; lane owns row r0 = threadIdx.x). BN=16: lane
// computes all 16 cols (B wave-uniform -> one s_load_dwordx16 per kk).
// No LDS, no barriers. A: lane-private row, 16B (uint4) / 8B (uint2) loads,
// double-buffered in registers within each phase.
// ---------------------------------------------------------------------------
#define BM 256
#define BN 16

typedef uint32_t u32;

__device__ __forceinline__ float cvt_ub(u32 x, int i) {
  return (float)((x >> (8 * i)) & 0xffu);   // folds to v_cvt_f32_ubyte_i
}

__global__ __launch_bounds__(256) void gemm_kernel(const uint8_t* __restrict__ enc,
                                                   const float* __restrict__ w1t,
                                                   float* __restrict__ g) {
  const int m0 = blockIdx.x * BM;
  const int n0 = blockIdx.y * BN;
  const int t  = threadIdx.x;

  // lane-private A row (4 waves x 64 lanes = 256 rows: r0 == t)
  const uint8_t* arow = enc + (size_t)(m0 + t) * KIN;

  float acc[16], tot[16];
#pragma unroll
  for (int c = 0; c < 16; c++) acc[c] = 0.0f;

  // 16 consecutive 16-kk tiles starting at k-offset ks (ks % 16 == 0)
  auto run16 = [&](int ks) {
    uint4 acur = *(const uint4*)(arow + ks);
    for (int tile = 0; tile < 16; tile++) {
      uint4 anext;
      if (tile < 15)
        anext = *(const uint4*)(arow + ks + (size_t)(tile + 1) * 16);
      const u32 w[4] = {acur.x, acur.y, acur.z, acur.w};
      const float* tb = w1t + (size_t)(ks + tile * 16) * HID + n0;
#pragma unroll
      for (int kk = 0; kk < 16; kk++) {
        float a0 = cvt_ub(w[kk >> 2], kk & 3);
        const float* brow = tb + (size_t)kk * HID;   // wave-uniform -> s_load
#pragma unroll
        for (int c = 0; c < 16; c++)
          acc[c] = __builtin_fmaf(a0, brow[c], acc[c]);  // exact product
      }
      acur = anext;
    }
  };
  // 8 kk starting at ks (ks % 8 == 0; uint2 load)
  auto run8 = [&](int ks) {
    uint2 av = *(const uint2*)(arow + ks);
    const u32 w[2] = {av.x, av.y};
    const float* tb = w1t + (size_t)ks * HID + n0;
#pragma unroll
    for (int kk = 0; kk < 8; kk++) {
      float a0 = cvt_ub(w[kk >> 2], kk & 3);
      const float* brow = tb + (size_t)kk * HID;
#pragma unroll
      for (int c = 0; c < 16; c++)
        acc[c] = __builtin_fmaf(a0, brow[c], acc[c]);
    }
  };

  // ---- panel 0: k 0..263 (ascending chain), then commit tot = acc ----
  run16(0);
  run8(256);
#pragma unroll
  for (int c = 0; c < 16; c++) { tot[c] = acc[c]; acc[c] = 0.0f; }
  // ---- panel 1: k 264..527, commit tot = rn(tot + acc) ----
  run8(264);
  run16(272);
#pragma unroll
  for (int c = 0; c < 16; c++) { tot[c] = __fadd_rn(tot[c], acc[c]); acc[c] = 0.0f; }
  // ---- panel 2: k 528..783 ----
  run16(528);

  // epilogue: g = 0.5 * rn(tot + P2)  (exact 0.5)
  float* o0 = g + (size_t)(m0 + t) * HID + n0;
#pragma unroll
  for (int c = 0; c < 16; c += 4) {
    float4 v0;
    v0.x = __fmul_rn(0.5f, __fadd_rn(tot[c + 0], acc[c + 0]));
    v0.y = __fmul_rn(0.5f, __fadd_rn(tot[c + 1], acc[c + 1]));
    v0.z = __fmul_rn(0.5f, __fadd_rn(tot[c + 2], acc[c + 2]));
    v0.w = __fmul_rn(0.5f, __fadd_rn(tot[c + 3], acc[c + 3]));
    *(float4*)(o0 + c) = v0;
  }
}

// ---------------------------------------------------------------------------
// Kernel 3: membrane update + spike + mem2 accumulation (g pre-combined).
// m = rn(rn(0.95f*mem) + rn(0.05f*g)) — mul/mul/add; products NOT exact here,
// so FMA contraction would change bits — keep split __fmul_rn/__fadd_rn.
// ---------------------------------------------------------------------------
__global__ __launch_bounds__(256) void update_kernel(const float* __restrict__ g,
                                                     float* __restrict__ mem1,
                                                     const float* __restrict__ w2,
                                                     float* __restrict__ mem2) {
  __shared__ float w2s[NOUT * HID];   // 32 KB
  for (int i = threadIdx.x; i < NOUT * HID; i += 256) w2s[i] = w2[i];
  __syncthreads();

  const int wave = threadIdx.x / 64;
  const int lane = threadIdx.x % 64;
  const int b = blockIdx.x * 4 + wave;

  const float* grow = g + (size_t)b * HID;
  float* mrow = mem1 + (size_t)b * HID;

  float acc[NOUT];
#pragma unroll
  for (int i = 0; i < NOUT; i++) acc[i] = 0.0f;

  for (int j = lane; j < HID; j += 64) {
    float m = __fadd_rn(__fmul_rn(0.95f, mrow[j]), __fmul_rn(0.05f, grow[j]));
    bool spike = __fadd_rn(m, -1.0f) > 0.0f;
    mrow[j] = spike ? __fadd_rn(m, -1.0f) : m;
    if (spike) {
#pragma unroll
      for (int i = 0; i < NOUT; i++) acc[i] += w2s[i * HID + j];
    }
  }
  // mem2 never feeds back into spike decisions: reduction-order noise ~1e-7
  // << 3.6e-3 threshold, no need to replicate ref's order here.
#pragma unroll
  for (int i = 0; i < NOUT; i++) {
    float v = acc[i];
    for (int off = 32; off > 0; off >>= 1) v += __shfl_down(v, off);
    if (lane == 0) mem2[(size_t)b * NOUT + i] += v;
  }
}

// ---------------------------------------------------------------------------
// Kernel 4: out = mem2 / num_steps
// ---------------------------------------------------------------------------
__global__ __launch_bounds__(256) void finalize_kernel(const float* __restrict__ mem2,
                                                       const int* __restrict__ ns,
                                                       float* __restrict__ out) {
  int i = blockIdx.x * blockDim.x + threadIdx.x;
  if (i < BSZ * NOUT) out[i] = mem2[i] / (float)(*ns);
}

// ---------------------------------------------------------------------------
extern "C" void kernel_launch(void* const* d_in, const int* in_sizes, int n_in,
                              void* d_out, int out_size, void* d_ws, size_t ws_size,
                              hipStream_t stream) {
  const float* inp = (const float*)d_in[0];
  const float* w1  = (const float*)d_in[1];
  const float* w2  = (const float*)d_in[2];
  const int*   dns = (const int*)d_in[3];
  float* out = (float*)d_out;

  char* ws = (char*)d_ws;
  size_t off = 0;
  uint8_t* enc = (uint8_t*)(ws + off);  off += (size_t)BSZ * KIN;          // 6.4 MB
  off = (off + 255) & ~(size_t)255;
  float* w1t  = (float*)(ws + off);     off += (size_t)KIN * HID * 4;      // 2.5 MB
  float* g    = (float*)(ws + off);     off += (size_t)BSZ * HID * 4;      // 26.2 MB
  float* mem1 = (float*)(ws + off);     off += (size_t)BSZ * HID * 4;      // 26.2 MB
  float* mem2 = (float*)(ws + off);     off += (size_t)BSZ * NOUT * 4;     // 0.33 MB

  (void)hipMemsetAsync(mem1, 0, (size_t)BSZ * HID * 4, stream);
  (void)hipMemsetAsync(mem2, 0, (size_t)BSZ * NOUT * 4, stream);

  // one-time transpose (w1 constant across steps)
  transpose_kernel<<<(KIN * HID + 255) / 256, 256, 0, stream>>>(w1, w1t);

  // Step keys: partitionable split — key_t = threefry((0,42), (0,t)).
  uint32_t keys[NSTEP][2];
  for (int t = 0; t < NSTEP; t++)
    threefry2x32(0u, 42u, 0u, (uint32_t)t, &keys[t][0], &keys[t][1]);

  const int n_elem = BSZ * KIN;
  for (int t = 0; t < NSTEP; t++) {
    enc_kernel<<<(n_elem + 255) / 256, 256, 0, stream>>>(inp, enc, keys[t][0], keys[t][1]);
    gemm_kernel<<<dim3(BSZ / BM, HID / BN), 256, 0, stream>>>(enc, w1t, g);
    update_kernel<<<BSZ / 4, 256, 0, stream>>>(g, mem1, w2, mem2);
  }
  finalize_kernel<<<(BSZ * NOUT + 255) / 256, 256, 0, stream>>>(mem2, dns, out);
}